// Round 15
// baseline (376.821 us; speedup 1.0000x reference)
//
#include <hip/hip_runtime.h>

#define M_TOTAL 65536   // B*T rows
#define DDIM    128     // latent dim (GEMM K)
#define KCODES  1024    // codebook size (GEMM N)
#define NQ      8       // RVQ stages
#define RROWS   64      // rows per block -> 1024 blocks
#define NC      64      // codes per Es chunk
#define NCHUNKS (KCODES / NC)          // 16
#define CHUNK_B (NC * DDIM * 2)        // 16384 B per f16 chunk (single buffer)
#define BIAS    320.0f  // folded into acc init: keys strictly positive (validated r9-r14)
#define THRQ    0.106f  // screen-unit flag threshold = validated 0.075 + 0.031 quant guard

typedef _Float16 half8 __attribute__((ext_vector_type(8)));
typedef float    f32x4 __attribute__((ext_vector_type(4)));
typedef unsigned u32x2 __attribute__((ext_vector_type(2)));

__device__ __forceinline__ unsigned umx(unsigned a, unsigned b) { return a > b ? a : b; }
__device__ __forceinline__ unsigned umn(unsigned a, unsigned b) { return a < b ? a : b; }

// direct global->LDS copy, 16 B per lane; LDS dest is wave-uniform base + lane*16
__device__ __forceinline__ void gld_lds16(const void* g, void* l) {
  __builtin_amdgcn_global_load_lds(
      (const __attribute__((address_space(1))) unsigned int*)g,
      (__attribute__((address_space(3))) unsigned int*)l, 16, 0, 0);
}

// ---------------- fused prep: ||e||^2 + f16 plane (PRE-SWIZZLED) in ONE pass ----
// (r14-validated.) One wave per code c: lane loads e[lane], e[lane+64] once;
// computes the round-1-verified enorm AND writes both f16 elements into the
// swizzled layout the screen's linear gld_lds expects:
//   element ei of code c -> c*128 + ((ei>>3) ^ (c&7))*8 + (ei&7)
__global__ __launch_bounds__(256) void prep_kernel(const float* __restrict__ embed,
                                                   _Float16* __restrict__ Ef16,
                                                   float* __restrict__ enorm) {
  const int c = blockIdx.x * 4 + (threadIdx.x >> 6);
  const int lane = threadIdx.x & 63;
  const float* e = embed + (size_t)c * DDIM;
  float v0 = e[lane];
  float v1 = e[lane + 64];
  {
    const int x7 = c & 7;
    int e0 = lane;
    int e1 = lane + 64;
    Ef16[(size_t)c * 128 + (((e0 >> 3) ^ x7) << 3) + (e0 & 7)] = (_Float16)v0;
    Ef16[(size_t)c * 128 + (((e1 >> 3) ^ x7) << 3) + (e1 & 7)] = (_Float16)v1;
  }
  float s = fmaf(v0, v0, v1 * v1);
  #pragma unroll
  for (int off = 32; off > 0; off >>= 1) s += __shfl_down(s, off);
  if (lane == 0) enorm[c] = s;
}

// ---------------- fused 8-stage RVQ: r9 single-buffer loop + setprio ----------------
// r9's structure verbatim (single 16 KB Es buffer, 2 barriers/chunk, staging
// issued between them so the epilogue covers the L2 latency; LDS ~52 KB ->
// 3 blocks/CU = 3 waves/SIMD) plus r14's s_setprio(1) around the MFMA cluster.
// Rationale: r9 == r10 without prio (330 vs 326); prio's gain scales with
// phase diversity (T5), and 3 independent block phase-clocks per CU arbitrate
// better than 2 while 3 waves/SIMD cover the shorter drain window. All
// arithmetic absmax-0-validated through r14 (packed sortable keys, THRQ quant
// guard, candidate fixup with sequential-k fmaf chain, 2.0f*acc-enorm,
// lowest-index ties, LDS-resident residual).
__global__ __launch_bounds__(256, 3) void rvq_fused(
    const float* __restrict__ x,          // [M_TOTAL][DDIM] f32
    const float* __restrict__ embed,      // [NQ][KCODES][DDIM] f32
    const _Float16* __restrict__ Ef16,    // [NQ][KCODES][DDIM] f16, pre-swizzled
    const float* __restrict__ enorm,      // [NQ][KCODES]
    int* __restrict__ codes)              // [NQ][M_TOTAL]
{
  __shared__ __attribute__((aligned(16))) float resid[RROWS][132];   // 33792 B
  __shared__ __attribute__((aligned(16))) char EsU[CHUNK_B];         // 16384 B (Es / cand)
  __shared__ unsigned redk[RROWS][2][2];                             // 1024 B
  __shared__ int bcode[RROWS];
  __shared__ int frows[RROWS];
  __shared__ int fcnt;

  const int tid = threadIdx.x;
  const int wv = tid >> 6;
  const int lane = tid & 63;
  const int l15 = lane & 15;
  const int q = lane >> 4;
  const int rw = wv & 1;          // row-half of the 2x2 wave grid
  const int cw = wv >> 1;         // code-half
  const int row_base = blockIdx.x * RROWS;
  const int rx = cw * 32 + l15;   // B-frag row within chunk (ct=0); ct=1 adds 16
  const int xr = rx & 7;          // Es bank swizzle key (rx and rx+16 share it)

  // ---- x -> LDS residual (once, coalesced) ----
  #pragma unroll
  for (int it = 0; it < 8; ++it) {
    int idx = it * 256 + tid;
    int r = idx >> 5, f4 = idx & 31;
    *(float4*)(&resid[r][f4 * 4]) = *(const float4*)(x + (size_t)(row_base + r) * DDIM + f4 * 4);
  }
  if (tid == 0) fcnt = 0;
  __syncthreads();

  for (int st = 0; st < NQ; ++st) {
    const _Float16* EfS = Ef16 + (size_t)st * KCODES * DDIM;
    const float* enS = enorm + (size_t)st * KCODES;
    const float* embS = embed + (size_t)st * KCODES * DDIM;

    // ---- f16 A-frags from LDS residual: af[rt][kc], rows rw*32+rt*16+l15 ----
    half8 af[2][4];
    #pragma unroll
    for (int rt = 0; rt < 2; ++rt) {
      const float* pa = &resid[rw * 32 + rt * 16 + l15][0];
      #pragma unroll
      for (int kc = 0; kc < 4; ++kc) {
        float4 x0 = *(const float4*)(pa + kc * 32 + q * 8);
        float4 x1 = *(const float4*)(pa + kc * 32 + q * 8 + 4);
        half8 h;
        h[0] = (_Float16)x0.x; h[1] = (_Float16)x0.y; h[2] = (_Float16)x0.z; h[3] = (_Float16)x0.w;
        h[4] = (_Float16)x1.x; h[5] = (_Float16)x1.y; h[6] = (_Float16)x1.z; h[7] = (_Float16)x1.w;
        af[rt][kc] = h;
      }
    }

    // ---- prologue: stage chunk 0 (linear gld_lds == pre-swizzled layout) ----
    {
      const char* g = (const char*)EfS;
      #pragma unroll
      for (int it = 0; it < 4; ++it) {
        const int off = it * 4096 + wv * 1024;
        gld_lds16(g + off + lane * 16, EsU + off);
      }
    }
    float enr0 = enS[cw * 32 + l15];
    float enr1 = enS[cw * 32 + 16 + l15];
    __syncthreads();              // chunk 0 staged (vmcnt drained); A-frag reads done

    // 8 key-pair streams/thread: stream (rt,reg) = row rw*32+rt*16+q*4+reg,
    // codes {cc*64 + cw*32 + ct*16 + l15}. 32 codes/stream.
    unsigned k1[8], k2[8];
    #pragma unroll
    for (int s = 0; s < 8; ++s) { k1[s] = 0u; k2[s] = 0u; }

    for (int cc = 0; cc < NCHUNKS; ++cc) {
      float nh0 = BIAS - 0.5f * enr0;  // biased: d = BIAS + dot - ||e||^2/2 > 0
      float nh1 = BIAS - 0.5f * enr1;
      if (cc + 1 < NCHUNKS) {          // pipeline next chunk's enorm
        enr0 = enS[(cc + 1) * NC + cw * 32 + l15];
        enr1 = enS[(cc + 1) * NC + cw * 32 + 16 + l15];
      }
      f32x4 acc[2][2];
      #pragma unroll
      for (int rt = 0; rt < 2; ++rt) {
        acc[rt][0] = (f32x4){nh0, nh0, nh0, nh0};
        acc[rt][1] = (f32x4){nh1, nh1, nh1, nh1};
      }

      __builtin_amdgcn_s_setprio(1);   // favor MFMA-entering waves (T5 regime:
      #pragma unroll                    // 3 independent blocks/CU, phase-diverse)
      for (int kc = 0; kc < 4; ++kc) {
        const int jswz = 16 * ((kc * 4 + q) ^ xr);
        half8 bf0 = *(const half8*)(EsU + rx * 256 + jswz);
        half8 bf1 = *(const half8*)(EsU + (rx + 16) * 256 + jswz);
        #pragma unroll
        for (int rt = 0; rt < 2; ++rt) {
          acc[rt][0] = __builtin_amdgcn_mfma_f32_16x16x32_f16(af[rt][kc], bf0, acc[rt][0], 0, 0, 0);
          acc[rt][1] = __builtin_amdgcn_mfma_f32_16x16x32_f16(af[rt][kc], bf1, acc[rt][1], 0, 0, 0);
        }
      }
      __builtin_amdgcn_s_setprio(0);
      __syncthreads();            // all Es reads done -> buffer overwritable

      if (cc + 1 < NCHUNKS) {     // issue next chunk; latency hides under epilogue
        const char* g = (const char*)EfS + (size_t)(cc + 1) * CHUNK_B;
        #pragma unroll
        for (int it = 0; it < 4; ++it) {
          const int off = it * 4096 + wv * 1024;
          gld_lds16(g + off + lane * 16, EsU + off);
        }
      }

      // ---- packed-key top-2 epilogue (distinct keys -> exact low-index ties) ----
      const unsigned revb = 1023u - (unsigned)(cc * NC + cw * 32 + l15);  // ct=0
      #pragma unroll
      for (int rt = 0; rt < 2; ++rt)
        #pragma unroll
        for (int reg = 0; reg < 4; ++reg) {
          const int s = rt * 4 + reg;
          unsigned kk0 = (__float_as_uint(acc[rt][0][reg]) & 0xFFFFFC00u) | revb;
          k2[s] = umx(umn(kk0, k1[s]), k2[s]);
          k1[s] = umx(k1[s], kk0);
          unsigned kk1 = (__float_as_uint(acc[rt][1][reg]) & 0xFFFFFC00u) | (revb - 16u);
          k2[s] = umx(umn(kk1, k1[s]), k2[s]);
          k1[s] = umx(k1[s], kk1);
        }
      __syncthreads();            // next chunk staged (vmcnt drained)
    }
    // EsU dead -> candidate table [row][cw*16+l15] = {k1,k2} (8 B/stream, 16 KB)

    // ---- candidate dump (pre-merge per-stream top-2) ----
    #pragma unroll
    for (int rt = 0; rt < 2; ++rt)
      #pragma unroll
      for (int reg = 0; reg < 4; ++reg) {
        const int row = rw * 32 + rt * 16 + q * 4 + reg;
        u32x2 kv = {k1[rt * 4 + reg], k2[rt * 4 + reg]};
        *(u32x2*)(EsU + row * 256 + (cw * 16 + l15) * 8) = kv;
      }

    // ---- merge top-2 across the 16 l15-lanes sharing each row (disjoint codes) ----
    #pragma unroll
    for (int s = 0; s < 8; ++s) {
      #pragma unroll
      for (int off = 1; off < 16; off <<= 1) {
        unsigned o1 = __shfl_xor(k1[s], off);
        unsigned o2 = __shfl_xor(k2[s], off);
        unsigned mn = umn(k1[s], o1);
        k1[s] = umx(k1[s], o1);
        k2[s] = umx(mn, umx(k2[s], o2));
      }
    }
    if (l15 == 0) {
      #pragma unroll
      for (int rt = 0; rt < 2; ++rt)
        #pragma unroll
        for (int reg = 0; reg < 4; ++reg) {
          const int row = rw * 32 + rt * 16 + q * 4 + reg;
          redk[row][cw][0] = k1[rt * 4 + reg];
          redk[row][cw][1] = k2[rt * 4 + reg];
        }
    }
    __syncthreads();              // cand table + redk visible

    // ---- final per-row merge (2 cw halves), flag into block-local list ----
    if (tid < RROWS) {
      unsigned a1 = redk[tid][0][0], a2 = redk[tid][0][1];
      unsigned b1 = redk[tid][1][0], b2 = redk[tid][1][1];
      unsigned f1 = umx(a1, b1);
      unsigned f2 = umx(umn(a1, b1), umx(a2, b2));
      bcode[tid] = 1023 - (int)(f1 & 1023u);
      float d1 = __uint_as_float(f1 & 0xFFFFFC00u);
      float d2 = __uint_as_float(f2 & 0xFFFFFC00u);
      if (d1 - d2 <= THRQ) {
        int p = atomicAdd(&fcnt, 1);
        frows[p] = tid;
      }
    }
    __syncthreads();              // flags + bcode visible
    const int nf = fcnt;

    // ---- exact candidate fixup: one wave per flagged row, lane per candidate ----
    // 64 candidates = 32 streams x top-2. Validated arithmetic: sequential-k
    // fmaf chain, 2.0f*acc - enorm (unbiased exact scale), lowest-index ties.
    for (int f = wv; f < nf; f += 4) {
      const int r = frows[f];
      const unsigned key = *(const unsigned*)(EsU + r * 256 + (lane >> 1) * 8 + (lane & 1) * 4);
      const int c = 1023 - (int)(key & 1023u);
      const float* rv = &resid[r][0];                // LDS, wave-uniform row
      const float* ev = embS + (size_t)c * DDIM;     // per-lane code row (L2-hot)
      float a = 0.f;
      #pragma unroll 4
      for (int k4 = 0; k4 < 32; ++k4) {
        float4 rr = *(const float4*)(rv + k4 * 4);
        float4 e4 = *(const float4*)(ev + k4 * 4);
        a = fmaf(rr.x, e4.x, a); a = fmaf(rr.y, e4.y, a);
        a = fmaf(rr.z, e4.z, a); a = fmaf(rr.w, e4.w, a);
      }
      float bv = 2.0f * a - enS[c];
      int bi = c;
      #pragma unroll
      for (int off = 32; off > 0; off >>= 1) {
        float o = __shfl_down(bv, off);
        int oi = __shfl_down(bi, off);
        if (o > bv || (o == bv && oi < bi)) { bv = o; bi = oi; }
      }
      if (lane == 0) bcode[r] = bi;
    }
    __syncthreads();              // corrected bcode visible
    if (tid == 0) fcnt = 0;       // next write behind >=1 barrier, reads done

    // ---- codes out + exact f32 residual update in LDS (final codes) ----
    if (tid < RROWS) codes[(size_t)st * M_TOTAL + row_base + tid] = bcode[tid];
    if (st < NQ - 1) {
      #pragma unroll
      for (int it = 0; it < 8; ++it) {
        int idx = it * 256 + tid;
        int r = idx >> 5, f4 = idx & 31;
        float4 e = *(const float4*)(embS + (size_t)bcode[r] * DDIM + f4 * 4);
        float4 a = *(const float4*)(&resid[r][f4 * 4]);
        a.x -= e.x; a.y -= e.y; a.z -= e.z; a.w -= e.w;
        *(float4*)(&resid[r][f4 * 4]) = a;   // owner-exclusive (r,f4)
      }
    }
    __syncthreads();              // resid update + fcnt reset ordered vs next stage
  }
}

// ================= fallback: round-2 verified exact-fp32 kernel =================
#define F_NCHUNK  256
#define F_KC      16
#define F_AS_STRIDE 68
#define F_ES_STRIDE 260

__global__ __launch_bounds__(256) void enorm_only_kernel(const float* __restrict__ embed,
                                                         float* __restrict__ enorm) {
  int c = blockIdx.x * 4 + (threadIdx.x >> 6);
  int lane = threadIdx.x & 63;
  const float* e = embed + (size_t)c * DDIM;
  float v0 = e[lane];
  float v1 = e[lane + 64];
  float s = fmaf(v0, v0, v1 * v1);
  #pragma unroll
  for (int off = 32; off > 0; off >>= 1) s += __shfl_down(s, off);
  if (lane == 0) enorm[c] = s;
}

__global__ __launch_bounds__(256, 3) void rvq_stage_kernel(
    const float* __restrict__ rin, float* __restrict__ rout,
    const float* __restrict__ embed, const float* __restrict__ enorm,
    int* __restrict__ codes)
{
  __shared__ float smem[DDIM * F_AS_STRIDE + F_KC * F_ES_STRIDE + F_NCHUNK];
  float* As  = smem;
  float* Es  = smem + DDIM * F_AS_STRIDE;
  float* Ens = Es + F_KC * F_ES_STRIDE;
  float* red_v = Es;
  int*   red_i = (int*)(Es + 64 * 33);
  int*   bcode = (int*)(Es + 2 * 64 * 33);

  const int tid = threadIdx.x;
  const int tx = tid & 31;
  const int ty = tid >> 5;
  const int row_base = blockIdx.x * 64;

  #pragma unroll
  for (int it = 0; it < 8; ++it) {
    int idx = it * 256 + tid;
    int r = idx >> 5, f4 = idx & 31;
    float4 v = *(const float4*)(rin + (size_t)(row_base + r) * DDIM + f4 * 4);
    As[(4 * f4 + 0) * F_AS_STRIDE + r] = v.x;
    As[(4 * f4 + 1) * F_AS_STRIDE + r] = v.y;
    As[(4 * f4 + 2) * F_AS_STRIDE + r] = v.z;
    As[(4 * f4 + 3) * F_AS_STRIDE + r] = v.w;
  }

  float best[8]; int bidx[8];
  #pragma unroll
  for (int i = 0; i < 8; ++i) { best[i] = -3.0e38f; bidx[i] = 0x7fffffff; }

  for (int nc = 0; nc < KCODES / F_NCHUNK; ++nc) {
    float acc[8][8];
    #pragma unroll
    for (int i = 0; i < 8; ++i)
      #pragma unroll
      for (int j = 0; j < 8; ++j) acc[i][j] = 0.0f;

    for (int kc = 0; kc < DDIM / F_KC; ++kc) {
      __syncthreads();
      #pragma unroll
      for (int it = 0; it < 4; ++it) {
        int idx = it * 256 + tid;
        int c = idx >> 2, f4 = idx & 3;
        float4 v = *(const float4*)(embed + (size_t)(nc * F_NCHUNK + c) * DDIM + kc * F_KC + f4 * 4);
        Es[(4 * f4 + 0) * F_ES_STRIDE + c] = v.x;
        Es[(4 * f4 + 1) * F_ES_STRIDE + c] = v.y;
        Es[(4 * f4 + 2) * F_ES_STRIDE + c] = v.z;
        Es[(4 * f4 + 3) * F_ES_STRIDE + c] = v.w;
      }
      if (kc == 0) Ens[tid] = enorm[nc * F_NCHUNK + tid];
      __syncthreads();

      const float* pa = As + kc * F_KC * F_AS_STRIDE + ty * 8;
      const float* pe = Es + 4 * tx;
      #pragma unroll 4
      for (int k = 0; k < F_KC; ++k) {
        float4 a0 = *(const float4*)(pa + k * F_AS_STRIDE);
        float4 a1 = *(const float4*)(pa + k * F_AS_STRIDE + 4);
        float4 e0 = *(const float4*)(pe + k * F_ES_STRIDE);
        float4 e1 = *(const float4*)(pe + k * F_ES_STRIDE + 128);
        float aa[8] = {a0.x, a0.y, a0.z, a0.w, a1.x, a1.y, a1.z, a1.w};
        float ee[8] = {e0.x, e0.y, e0.z, e0.w, e1.x, e1.y, e1.z, e1.w};
        #pragma unroll
        for (int i = 0; i < 8; ++i)
          #pragma unroll
          for (int j = 0; j < 8; ++j)
            acc[i][j] = fmaf(aa[i], ee[j], acc[i][j]);
      }
    }

    #pragma unroll
    for (int j = 0; j < 8; ++j) {
      int c_local = (j < 4) ? (4 * tx + j) : (128 + 4 * tx + (j - 4));
      float en = Ens[c_local];
      int cg = nc * F_NCHUNK + c_local;
      #pragma unroll
      for (int i = 0; i < 8; ++i) {
        float dist = 2.0f * acc[i][j] - en;
        if (dist > best[i] || (dist == best[i] && cg < bidx[i])) { best[i] = dist; bidx[i] = cg; }
      }
    }
  }

  __syncthreads();
  #pragma unroll
  for (int i = 0; i < 8; ++i) {
    red_v[(ty * 8 + i) * 33 + tx] = best[i];
    red_i[(ty * 8 + i) * 33 + tx] = bidx[i];
  }
  __syncthreads();
  if (tid < 64) {
    float bv = red_v[tid * 33]; int bi = red_i[tid * 33];
    #pragma unroll
    for (int t = 1; t < 32; ++t) {
      float v = red_v[tid * 33 + t]; int ix = red_i[tid * 33 + t];
      if (v > bv || (v == bv && ix < bi)) { bv = v; bi = ix; }
    }
    codes[row_base + tid] = bi;
    bcode[tid] = bi;
  }
  __syncthreads();
  #pragma unroll
  for (int it = 0; it < 32; ++it) {
    int idx = it * 256 + tid;
    int r = idx >> 7, d = idx & 127;
    float e = embed[(size_t)bcode[r] * DDIM + d];
    rout[(size_t)(row_base + r) * DDIM + d] = As[d * F_AS_STRIDE + r] - e;
  }
}

extern "C" void kernel_launch(void* const* d_in, const int* in_sizes, int n_in,
                              void* d_out, int out_size, void* d_ws, size_t ws_size,
                              hipStream_t stream) {
  (void)in_sizes; (void)n_in; (void)out_size;
  const float* x = (const float*)d_in[0];
  const float* embed = (const float*)d_in[1];
  int* codes = (int*)d_out;

  const size_t E16_BYTES = (size_t)NQ * KCODES * DDIM * 2;        // 2 MB f16 codebook
  const size_t EN_BYTES  = (size_t)NQ * KCODES * 4;               // 32 KB
  const size_t need = E16_BYTES + EN_BYTES + 256;

  if (ws_size >= need) {
    char* w = (char*)d_ws;
    _Float16* Ef16 = (_Float16*)w;     w += E16_BYTES;
    float* enorm   = (float*)w;

    prep_kernel<<<dim3(NQ * KCODES / 4), dim3(256), 0, stream>>>(embed, Ef16, enorm);
    rvq_fused<<<dim3(M_TOTAL / RROWS), dim3(256), 0, stream>>>(
        x, embed, Ef16, enorm, codes);
  } else {
    // fallback: verified round-2 exact-fp32 path
    const size_t resid_elems = (size_t)M_TOTAL * DDIM;
    const bool ws_ok = ws_size >= (resid_elems + (size_t)NQ * KCODES) * sizeof(float);
    float* resid = ws_ok ? (float*)d_ws : (float*)d_in[0];
    float* enorm = ws_ok ? ((float*)d_ws + resid_elems) : (float*)d_ws;

    enorm_only_kernel<<<dim3(NQ * KCODES / 4), dim3(256), 0, stream>>>(embed, enorm);
    for (int q = 0; q < NQ; ++q) {
      const float* rin = (q == 0) ? x : resid;
      rvq_stage_kernel<<<dim3(M_TOTAL / 64), dim3(256), 0, stream>>>(
          rin, resid, embed + (size_t)q * KCODES * DDIM,
          enorm + (size_t)q * KCODES, codes + (size_t)q * M_TOTAL);
    }
  }
}

// Round 16
// 337.239 us; speedup vs baseline: 1.1174x; 1.1174x over previous
//
#include <hip/hip_runtime.h>

#define M_TOTAL 65536   // B*T rows
#define DDIM    128     // latent dim (GEMM K)
#define KCODES  1024    // codebook size (GEMM N)
#define NQ      8       // RVQ stages
#define RROWS   64      // rows per block -> 1024 blocks, 2/CU co-resident
#define NC      64      // codes per Es chunk
#define NCHUNKS (KCODES / NC)          // 16
#define CHUNK_B (NC * DDIM * 2)        // 16384 B per f16 chunk
#define BIAS    320.0f  // folded into acc init: keys strictly positive (validated r9-r14)
#define THRQ    0.106f  // screen-unit flag threshold = validated 0.075 + 0.031 quant guard

typedef _Float16 half8 __attribute__((ext_vector_type(8)));
typedef float    f32x4 __attribute__((ext_vector_type(4)));
typedef unsigned u32x2 __attribute__((ext_vector_type(2)));

__device__ __forceinline__ unsigned umx(unsigned a, unsigned b) { return a > b ? a : b; }
__device__ __forceinline__ unsigned umn(unsigned a, unsigned b) { return a < b ? a : b; }

// direct global->LDS copy, 16 B per lane; LDS dest is wave-uniform base + lane*16
__device__ __forceinline__ void gld_lds16(const void* g, void* l) {
  __builtin_amdgcn_global_load_lds(
      (const __attribute__((address_space(1))) unsigned int*)g,
      (__attribute__((address_space(3))) unsigned int*)l, 16, 0, 0);
}

// ---------------- fused prep: ||e||^2 + f16 plane (PRE-SWIZZLED) in ONE pass ----
// (r14-validated.) One wave per code c: lane loads e[lane], e[lane+64] once;
// computes the round-1-verified enorm AND writes both f16 elements into the
// swizzled layout the screen's linear gld_lds expects:
//   element ei of code c -> c*128 + ((ei>>3) ^ (c&7))*8 + (ei&7)
__global__ __launch_bounds__(256) void prep_kernel(const float* __restrict__ embed,
                                                   _Float16* __restrict__ Ef16,
                                                   float* __restrict__ enorm) {
  const int c = blockIdx.x * 4 + (threadIdx.x >> 6);
  const int lane = threadIdx.x & 63;
  const float* e = embed + (size_t)c * DDIM;
  float v0 = e[lane];
  float v1 = e[lane + 64];
  {
    const int x7 = c & 7;
    int e0 = lane;
    int e1 = lane + 64;
    Ef16[(size_t)c * 128 + (((e0 >> 3) ^ x7) << 3) + (e0 & 7)] = (_Float16)v0;
    Ef16[(size_t)c * 128 + (((e1 >> 3) ^ x7) << 3) + (e1 & 7)] = (_Float16)v1;
  }
  float s = fmaf(v0, v0, v1 * v1);
  #pragma unroll
  for (int off = 32; off > 0; off >>= 1) s += __shfl_down(s, off);
  if (lane == 0) enorm[c] = s;
}

// ---------------- fused 8-stage RVQ: LDS residual + dbuf Es + packed-key top-2 ----
// Round-14 kernel verbatim -- the session's best measured configuration
// (306 us fused / 339 us total, absmax 0). Structure: LDS-resident residual
// (zero resid HBM traffic), double-buffered Es with ONE barrier per chunk
// (loads for chunk cc+1 issued first in the body of cc -> full MFMA+epilogue
// window covers the L2 latency), packed sortable-key top-2 (BIAS-folded,
// branchless umn/umx, exact lowest-index ties), s_setprio(1) around the MFMA
// cluster (pays in the 2-independent-blocks/CU phase-diverse regime, +6%),
// candidate fixup (64 exact f32 re-evals/flagged row: sequential-k fmaf chain,
// 2.0f*acc - enorm, lowest-index ties). Exploration rounds 9-15 established
// this as the plateau: single-buffer+3blk (r15) -13%, 8-wave blocks (r11/r12)
// spill or no co-residency, direct-L2 B (r13) -2.1x, barrier-free variants
// latency-bound. 2 blocks/CU x 4 waves, VGPR 92, LDS 68.6 KB.
__global__ __launch_bounds__(256, 2) void rvq_fused(
    const float* __restrict__ x,          // [M_TOTAL][DDIM] f32
    const float* __restrict__ embed,      // [NQ][KCODES][DDIM] f32
    const _Float16* __restrict__ Ef16,    // [NQ][KCODES][DDIM] f16, pre-swizzled
    const float* __restrict__ enorm,      // [NQ][KCODES]
    int* __restrict__ codes)              // [NQ][M_TOTAL]
{
  __shared__ __attribute__((aligned(16))) float resid[RROWS][132];   // 33792 B
  __shared__ __attribute__((aligned(16))) char EsU[2 * CHUNK_B];     // 32768 B (dbuf / cand)
  __shared__ unsigned redk[RROWS][2][2];                             // 1024 B
  __shared__ int bcode[RROWS];
  __shared__ int frows[RROWS];
  __shared__ int fcnt;

  const int tid = threadIdx.x;
  const int wv = tid >> 6;
  const int lane = tid & 63;
  const int l15 = lane & 15;
  const int q = lane >> 4;
  const int rw = wv & 1;          // row-half of the 2x2 wave grid
  const int cw = wv >> 1;         // code-half
  const int row_base = blockIdx.x * RROWS;
  const int rx = cw * 32 + l15;   // B-frag row within chunk (ct=0); ct=1 adds 16
  const int xr = rx & 7;          // Es bank swizzle key (rx and rx+16 share it)

  // ---- x -> LDS residual (once, coalesced) ----
  #pragma unroll
  for (int it = 0; it < 8; ++it) {
    int idx = it * 256 + tid;
    int r = idx >> 5, f4 = idx & 31;
    *(float4*)(&resid[r][f4 * 4]) = *(const float4*)(x + (size_t)(row_base + r) * DDIM + f4 * 4);
  }
  if (tid == 0) fcnt = 0;
  __syncthreads();

  for (int st = 0; st < NQ; ++st) {
    const _Float16* EfS = Ef16 + (size_t)st * KCODES * DDIM;
    const float* enS = enorm + (size_t)st * KCODES;
    const float* embS = embed + (size_t)st * KCODES * DDIM;

    // ---- f16 A-frags from LDS residual: af[rt][kc], rows rw*32+rt*16+l15 ----
    half8 af[2][4];
    #pragma unroll
    for (int rt = 0; rt < 2; ++rt) {
      const float* pa = &resid[rw * 32 + rt * 16 + l15][0];
      #pragma unroll
      for (int kc = 0; kc < 4; ++kc) {
        float4 x0 = *(const float4*)(pa + kc * 32 + q * 8);
        float4 x1 = *(const float4*)(pa + kc * 32 + q * 8 + 4);
        half8 h;
        h[0] = (_Float16)x0.x; h[1] = (_Float16)x0.y; h[2] = (_Float16)x0.z; h[3] = (_Float16)x0.w;
        h[4] = (_Float16)x1.x; h[5] = (_Float16)x1.y; h[6] = (_Float16)x1.z; h[7] = (_Float16)x1.w;
        af[rt][kc] = h;
      }
    }

    // ---- prologue: stage chunk 0 into buf 0 (linear gld_lds == swizzled layout) ----
    {
      const char* g = (const char*)EfS;
      #pragma unroll
      for (int it = 0; it < 4; ++it) {
        const int off = it * 4096 + wv * 1024;
        gld_lds16(g + off + lane * 16, EsU + off);
      }
    }
    float enr0 = enS[cw * 32 + l15];
    float enr1 = enS[cw * 32 + 16 + l15];
    __syncthreads();              // chunk 0 staged (vmcnt drained); A-frag reads done

    // 8 key-pair streams/thread: stream (rt,reg) = row rw*32+rt*16+q*4+reg,
    // codes {cc*64 + cw*32 + ct*16 + l15}. 32 codes/stream.
    unsigned k1[8], k2[8];
    #pragma unroll
    for (int s = 0; s < 8; ++s) { k1[s] = 0u; k2[s] = 0u; }

    for (int cc = 0; cc < NCHUNKS; ++cc) {
      const int cur = cc & 1;
      // issue next chunk FIRST: full MFMA+epilogue window covers the L2 latency
      if (cc + 1 < NCHUNKS) {
        const char* g = (const char*)EfS + (size_t)(cc + 1) * CHUNK_B;
        char* l = EsU + (cur ^ 1) * CHUNK_B;
        #pragma unroll
        for (int it = 0; it < 4; ++it) {
          const int off = it * 4096 + wv * 1024;
          gld_lds16(g + off + lane * 16, l + off);
        }
      }
      float nh0 = BIAS - 0.5f * enr0;  // biased: d = BIAS + dot - ||e||^2/2 > 0
      float nh1 = BIAS - 0.5f * enr1;
      if (cc + 1 < NCHUNKS) {          // pipeline next chunk's enorm
        enr0 = enS[(cc + 1) * NC + cw * 32 + l15];
        enr1 = enS[(cc + 1) * NC + cw * 32 + 16 + l15];
      }
      f32x4 acc[2][2];
      #pragma unroll
      for (int rt = 0; rt < 2; ++rt) {
        acc[rt][0] = (f32x4){nh0, nh0, nh0, nh0};
        acc[rt][1] = (f32x4){nh1, nh1, nh1, nh1};
      }

      const char* eb = EsU + cur * CHUNK_B;
      __builtin_amdgcn_s_setprio(1);   // favor MFMA-entering waves (T5 regime:
      #pragma unroll                    // 2 independent blocks/CU, phase-diverse)
      for (int kc = 0; kc < 4; ++kc) {
        const int jswz = 16 * ((kc * 4 + q) ^ xr);
        half8 bf0 = *(const half8*)(eb + rx * 256 + jswz);
        half8 bf1 = *(const half8*)(eb + (rx + 16) * 256 + jswz);
        #pragma unroll
        for (int rt = 0; rt < 2; ++rt) {
          acc[rt][0] = __builtin_amdgcn_mfma_f32_16x16x32_f16(af[rt][kc], bf0, acc[rt][0], 0, 0, 0);
          acc[rt][1] = __builtin_amdgcn_mfma_f32_16x16x32_f16(af[rt][kc], bf1, acc[rt][1], 0, 0, 0);
        }
      }
      __builtin_amdgcn_s_setprio(0);

      // ---- packed-key top-2 epilogue (distinct keys -> exact low-index ties) ----
      const unsigned revb = 1023u - (unsigned)(cc * NC + cw * 32 + l15);  // ct=0
      #pragma unroll
      for (int rt = 0; rt < 2; ++rt)
        #pragma unroll
        for (int reg = 0; reg < 4; ++reg) {
          const int s = rt * 4 + reg;
          unsigned kk0 = (__float_as_uint(acc[rt][0][reg]) & 0xFFFFFC00u) | revb;
          k2[s] = umx(umn(kk0, k1[s]), k2[s]);
          k1[s] = umx(k1[s], kk0);
          unsigned kk1 = (__float_as_uint(acc[rt][1][reg]) & 0xFFFFFC00u) | (revb - 16u);
          k2[s] = umx(umn(kk1, k1[s]), k2[s]);
          k1[s] = umx(k1[s], kk1);
        }
      __syncthreads();            // ONE barrier/chunk: next buf staged, cur consumed
    }
    // EsU dead -> candidate table [row][cw*16+l15] = {k1,k2} (8 B/stream, 16 KB)

    // ---- candidate dump (pre-merge per-stream top-2) ----
    #pragma unroll
    for (int rt = 0; rt < 2; ++rt)
      #pragma unroll
      for (int reg = 0; reg < 4; ++reg) {
        const int row = rw * 32 + rt * 16 + q * 4 + reg;
        u32x2 kv = {k1[rt * 4 + reg], k2[rt * 4 + reg]};
        *(u32x2*)(EsU + row * 256 + (cw * 16 + l15) * 8) = kv;
      }

    // ---- merge top-2 across the 16 l15-lanes sharing each row (disjoint codes) ----
    #pragma unroll
    for (int s = 0; s < 8; ++s) {
      #pragma unroll
      for (int off = 1; off < 16; off <<= 1) {
        unsigned o1 = __shfl_xor(k1[s], off);
        unsigned o2 = __shfl_xor(k2[s], off);
        unsigned mn = umn(k1[s], o1);
        k1[s] = umx(k1[s], o1);
        k2[s] = umx(mn, umx(k2[s], o2));
      }
    }
    if (l15 == 0) {
      #pragma unroll
      for (int rt = 0; rt < 2; ++rt)
        #pragma unroll
        for (int reg = 0; reg < 4; ++reg) {
          const int row = rw * 32 + rt * 16 + q * 4 + reg;
          redk[row][cw][0] = k1[rt * 4 + reg];
          redk[row][cw][1] = k2[rt * 4 + reg];
        }
    }
    __syncthreads();              // cand table + redk visible

    // ---- final per-row merge (2 cw halves), flag into block-local list ----
    if (tid < RROWS) {
      unsigned a1 = redk[tid][0][0], a2 = redk[tid][0][1];
      unsigned b1 = redk[tid][1][0], b2 = redk[tid][1][1];
      unsigned f1 = umx(a1, b1);
      unsigned f2 = umx(umn(a1, b1), umx(a2, b2));
      bcode[tid] = 1023 - (int)(f1 & 1023u);
      float d1 = __uint_as_float(f1 & 0xFFFFFC00u);
      float d2 = __uint_as_float(f2 & 0xFFFFFC00u);
      if (d1 - d2 <= THRQ) {
        int p = atomicAdd(&fcnt, 1);
        frows[p] = tid;
      }
    }
    __syncthreads();              // flags + bcode visible
    const int nf = fcnt;

    // ---- exact candidate fixup: one wave per flagged row, lane per candidate ----
    // 64 candidates = 32 streams x top-2. Validated arithmetic: sequential-k
    // fmaf chain, 2.0f*acc - enorm (unbiased exact scale), lowest-index ties.
    for (int f = wv; f < nf; f += 4) {
      const int r = frows[f];
      const unsigned key = *(const unsigned*)(EsU + r * 256 + (lane >> 1) * 8 + (lane & 1) * 4);
      const int c = 1023 - (int)(key & 1023u);
      const float* rv = &resid[r][0];                // LDS, wave-uniform row
      const float* ev = embS + (size_t)c * DDIM;     // per-lane code row (L2-hot)
      float a = 0.f;
      #pragma unroll 4
      for (int k4 = 0; k4 < 32; ++k4) {
        float4 rr = *(const float4*)(rv + k4 * 4);
        float4 e4 = *(const float4*)(ev + k4 * 4);
        a = fmaf(rr.x, e4.x, a); a = fmaf(rr.y, e4.y, a);
        a = fmaf(rr.z, e4.z, a); a = fmaf(rr.w, e4.w, a);
      }
      float bv = 2.0f * a - enS[c];
      int bi = c;
      #pragma unroll
      for (int off = 32; off > 0; off >>= 1) {
        float o = __shfl_down(bv, off);
        int oi = __shfl_down(bi, off);
        if (o > bv || (o == bv && oi < bi)) { bv = o; bi = oi; }
      }
      if (lane == 0) bcode[r] = bi;
    }
    __syncthreads();              // corrected bcode visible
    if (tid == 0) fcnt = 0;       // next write behind >=1 barrier, reads done

    // ---- codes out + exact f32 residual update in LDS (final codes) ----
    if (tid < RROWS) codes[(size_t)st * M_TOTAL + row_base + tid] = bcode[tid];
    if (st < NQ - 1) {
      #pragma unroll
      for (int it = 0; it < 8; ++it) {
        int idx = it * 256 + tid;
        int r = idx >> 5, f4 = idx & 31;
        float4 e = *(const float4*)(embS + (size_t)bcode[r] * DDIM + f4 * 4);
        float4 a = *(const float4*)(&resid[r][f4 * 4]);
        a.x -= e.x; a.y -= e.y; a.z -= e.z; a.w -= e.w;
        *(float4*)(&resid[r][f4 * 4]) = a;   // owner-exclusive (r,f4)
      }
    }
    __syncthreads();              // resid update + fcnt reset ordered vs next stage
  }
}

// ================= fallback: round-2 verified exact-fp32 kernel =================
#define F_NCHUNK  256
#define F_KC      16
#define F_AS_STRIDE 68
#define F_ES_STRIDE 260

__global__ __launch_bounds__(256) void enorm_only_kernel(const float* __restrict__ embed,
                                                         float* __restrict__ enorm) {
  int c = blockIdx.x * 4 + (threadIdx.x >> 6);
  int lane = threadIdx.x & 63;
  const float* e = embed + (size_t)c * DDIM;
  float v0 = e[lane];
  float v1 = e[lane + 64];
  float s = fmaf(v0, v0, v1 * v1);
  #pragma unroll
  for (int off = 32; off > 0; off >>= 1) s += __shfl_down(s, off);
  if (lane == 0) enorm[c] = s;
}

__global__ __launch_bounds__(256, 3) void rvq_stage_kernel(
    const float* __restrict__ rin, float* __restrict__ rout,
    const float* __restrict__ embed, const float* __restrict__ enorm,
    int* __restrict__ codes)
{
  __shared__ float smem[DDIM * F_AS_STRIDE + F_KC * F_ES_STRIDE + F_NCHUNK];
  float* As  = smem;
  float* Es  = smem + DDIM * F_AS_STRIDE;
  float* Ens = Es + F_KC * F_ES_STRIDE;
  float* red_v = Es;
  int*   red_i = (int*)(Es + 64 * 33);
  int*   bcode = (int*)(Es + 2 * 64 * 33);

  const int tid = threadIdx.x;
  const int tx = tid & 31;
  const int ty = tid >> 5;
  const int row_base = blockIdx.x * 64;

  #pragma unroll
  for (int it = 0; it < 8; ++it) {
    int idx = it * 256 + tid;
    int r = idx >> 5, f4 = idx & 31;
    float4 v = *(const float4*)(rin + (size_t)(row_base + r) * DDIM + f4 * 4);
    As[(4 * f4 + 0) * F_AS_STRIDE + r] = v.x;
    As[(4 * f4 + 1) * F_AS_STRIDE + r] = v.y;
    As[(4 * f4 + 2) * F_AS_STRIDE + r] = v.z;
    As[(4 * f4 + 3) * F_AS_STRIDE + r] = v.w;
  }

  float best[8]; int bidx[8];
  #pragma unroll
  for (int i = 0; i < 8; ++i) { best[i] = -3.0e38f; bidx[i] = 0x7fffffff; }

  for (int nc = 0; nc < KCODES / F_NCHUNK; ++nc) {
    float acc[8][8];
    #pragma unroll
    for (int i = 0; i < 8; ++i)
      #pragma unroll
      for (int j = 0; j < 8; ++j) acc[i][j] = 0.0f;

    for (int kc = 0; kc < DDIM / F_KC; ++kc) {
      __syncthreads();
      #pragma unroll
      for (int it = 0; it < 4; ++it) {
        int idx = it * 256 + tid;
        int c = idx >> 2, f4 = idx & 3;
        float4 v = *(const float4*)(embed + (size_t)(nc * F_NCHUNK + c) * DDIM + kc * F_KC + f4 * 4);
        Es[(4 * f4 + 0) * F_ES_STRIDE + c] = v.x;
        Es[(4 * f4 + 1) * F_ES_STRIDE + c] = v.y;
        Es[(4 * f4 + 2) * F_ES_STRIDE + c] = v.z;
        Es[(4 * f4 + 3) * F_ES_STRIDE + c] = v.w;
      }
      if (kc == 0) Ens[tid] = enorm[nc * F_NCHUNK + tid];
      __syncthreads();

      const float* pa = As + kc * F_KC * F_AS_STRIDE + ty * 8;
      const float* pe = Es + 4 * tx;
      #pragma unroll 4
      for (int k = 0; k < F_KC; ++k) {
        float4 a0 = *(const float4*)(pa + k * F_AS_STRIDE);
        float4 a1 = *(const float4*)(pa + k * F_AS_STRIDE + 4);
        float4 e0 = *(const float4*)(pe + k * F_ES_STRIDE);
        float4 e1 = *(const float4*)(pe + k * F_ES_STRIDE + 128);
        float aa[8] = {a0.x, a0.y, a0.z, a0.w, a1.x, a1.y, a1.z, a1.w};
        float ee[8] = {e0.x, e0.y, e0.z, e0.w, e1.x, e1.y, e1.z, e1.w};
        #pragma unroll
        for (int i = 0; i < 8; ++i)
          #pragma unroll
          for (int j = 0; j < 8; ++j)
            acc[i][j] = fmaf(aa[i], ee[j], acc[i][j]);
      }
    }

    #pragma unroll
    for (int j = 0; j < 8; ++j) {
      int c_local = (j < 4) ? (4 * tx + j) : (128 + 4 * tx + (j - 4));
      float en = Ens[c_local];
      int cg = nc * F_NCHUNK + c_local;
      #pragma unroll
      for (int i = 0; i < 8; ++i) {
        float dist = 2.0f * acc[i][j] - en;
        if (dist > best[i] || (dist == best[i] && cg < bidx[i])) { best[i] = dist; bidx[i] = cg; }
      }
    }
  }

  __syncthreads();
  #pragma unroll
  for (int i = 0; i < 8; ++i) {
    red_v[(ty * 8 + i) * 33 + tx] = best[i];
    red_i[(ty * 8 + i) * 33 + tx] = bidx[i];
  }
  __syncthreads();
  if (tid < 64) {
    float bv = red_v[tid * 33]; int bi = red_i[tid * 33];
    #pragma unroll
    for (int t = 1; t < 32; ++t) {
      float v = red_v[tid * 33 + t]; int ix = red_i[tid * 33 + t];
      if (v > bv || (v == bv && ix < bi)) { bv = v; bi = ix; }
    }
    codes[row_base + tid] = bi;
    bcode[tid] = bi;
  }
  __syncthreads();
  #pragma unroll
  for (int it = 0; it < 32; ++it) {
    int idx = it * 256 + tid;
    int r = idx >> 7, d = idx & 127;
    float e = embed[(size_t)bcode[r] * DDIM + d];
    rout[(size_t)(row_base + r) * DDIM + d] = As[d * F_AS_STRIDE + r] - e;
  }
}

extern "C" void kernel_launch(void* const* d_in, const int* in_sizes, int n_in,
                              void* d_out, int out_size, void* d_ws, size_t ws_size,
                              hipStream_t stream) {
  (void)in_sizes; (void)n_in; (void)out_size;
  const float* x = (const float*)d_in[0];
  const float* embed = (const float*)d_in[1];
  int* codes = (int*)d_out;

  const size_t E16_BYTES = (size_t)NQ * KCODES * DDIM * 2;        // 2 MB f16 codebook
  const size_t EN_BYTES  = (size_t)NQ * KCODES * 4;               // 32 KB
  const size_t need = E16_BYTES + EN_BYTES + 256;

  if (ws_size >= need) {
    char* w = (char*)d_ws;
    _Float16* Ef16 = (_Float16*)w;     w += E16_BYTES;
    float* enorm   = (float*)w;

    prep_kernel<<<dim3(NQ * KCODES / 4), dim3(256), 0, stream>>>(embed, Ef16, enorm);
    rvq_fused<<<dim3(M_TOTAL / RROWS), dim3(256), 0, stream>>>(
        x, embed, Ef16, enorm, codes);
  } else {
    // fallback: verified round-2 exact-fp32 path
    const size_t resid_elems = (size_t)M_TOTAL * DDIM;
    const bool ws_ok = ws_size >= (resid_elems + (size_t)NQ * KCODES) * sizeof(float);
    float* resid = ws_ok ? (float*)d_ws : (float*)d_in[0];
    float* enorm = ws_ok ? ((float*)d_ws + resid_elems) : (float*)d_ws;

    enorm_only_kernel<<<dim3(NQ * KCODES / 4), dim3(256), 0, stream>>>(embed, enorm);
    for (int q = 0; q < NQ; ++q) {
      const float* rin = (q == 0) ? x : resid;
      rvq_stage_kernel<<<dim3(M_TOTAL / 64), dim3(256), 0, stream>>>(
          rin, resid, embed + (size_t)q * KCODES * DDIM,
          enorm + (size_t)q * KCODES, codes + (size_t)q * M_TOTAL);
    }
  }
}